// Round 23
// baseline (69.716 us; speedup 1.0000x reference)
//
#include <hip/hip_runtime.h>

// R24 = LOOP-AMPLIFIED MEASUREMENT round (output still correct).
// p-loop runs 4x with W2 scaled 0.1 (4 * 0.1 = 0.4 total — identical math;
// linear init outside the rep loop). Opaque asm on xf each rep blocks CSE.
// Purpose: dur = F + W_fixed + 4*W_loop = 26.07 + 3*W_loop, AND if dur > 41us
// the kernel finally outranks the harness poison-fills in the rocprof top-5,
// exposing MfmaUtil/VALUBusy/Occupancy/LDS_CONFLICT for the real structure.
// R22 slope test: F=4.57, W=21.5. R23: occupancy 2->4 waves/SIMD = flat.
//
// out[b,o] = sum_h W2[o,h]*leaky(h) + b2[o],  h = W1[o]·x[b] + b1[o]

#define B_DIM 32768
#define I_DIM 16
#define O_DIM 16
#define H_DIM 512

typedef _Float16 f16x4 __attribute__((ext_vector_type(4)));
typedef _Float16 f16x8 __attribute__((ext_vector_type(8)));
typedef __fp16   h16x2 __attribute__((ext_vector_type(2)));   // cvt_pkrtz native
typedef float    f32x4 __attribute__((ext_vector_type(4)));
typedef int      i32x2 __attribute__((ext_vector_type(2)));
typedef int      i32x4 __attribute__((ext_vector_type(4)));

#define LOOP_REPS 4
#define W2SCALE   0.1f   // 0.4 / LOOP_REPS (exact in fp32)

// 256 blocks x 512 thr (8 waves), 1 block/CU. o = blk&15, grp = blk>>4 (16).
__global__ __launch_bounds__(512, 2) void mlp_fused(
    const float* __restrict__ x, const float* __restrict__ W1,
    const float* __restrict__ b1, const float* __restrict__ W2,
    const float* __restrict__ b2, float* __restrict__ out) {
    __shared__ f16x8 sm_a1[1024];     // [p][lane] stage1-A pairs   16 KiB
    __shared__ f16x8 sm_w2[1024];     // [p][lane] stage2-B (0.1x)  16 KiB
    __shared__ float sm_b1[512];      //  2 KiB
    __shared__ f32x4 red4[512];       //  8 KiB (v partials)
    __shared__ float red[512];        //  2 KiB (c0 partials)
    __shared__ float v_sm[16];
    __shared__ float c_sm;

    const int tid = threadIdx.x;
    const int o   = blockIdx.x & 15;
    const int grp = blockIdx.x >> 4;
    const float* W1o = W1 + (size_t)o * H_DIM * I_DIM;
    const float* W2o = W2 + (size_t)o * H_DIM;
    const float* b1o = b1 + (size_t)o * H_DIM;

    const int lane = tid & 63, w = tid >> 6;
    const int col = lane & 15, kg = lane >> 4;

    // ---- phase A: stage fragments + fused v-partials ----
    f32x4 vpart = {0.f, 0.f, 0.f, 0.f};
#pragma unroll
    for (int i = 0; i < 2; ++i) {
        const int e = tid + 512 * i;          // 0..1023 = [p][lane]
        const int l = e & 63, p = e >> 6;
        const int row = l & 15, kgs = l >> 4;
        const float* a_base = W1o + ((size_t)(2 * p * 16 + row) * I_DIM + kgs * 4);
        const f32x4 a0 = *reinterpret_cast<const f32x4*>(a_base);
        const f32x4 a1v = *reinterpret_cast<const f32x4*>(a_base + 16 * I_DIM);
        f16x8 va;
#pragma unroll
        for (int j = 0; j < 4; ++j) { va[j] = (_Float16)a0[j]; va[4 + j] = (_Float16)a1v[j]; }
        sm_a1[e] = va;
        const float w2a = W2o[2 * p * 16 + row];
        const float w2b = W2o[2 * p * 16 + 16 + row];
#pragma unroll
        for (int j = 0; j < 4; ++j)
            vpart[j] = fmaf(w2b, a1v[j], fmaf(w2a, a0[j], vpart[j]));
        const float* w_base = W2o + p * 32 + kgs * 4;
        const f32x4 w0 = *reinterpret_cast<const f32x4*>(w_base);
        const f32x4 w1v = *reinterpret_cast<const f32x4*>(w_base + 16);
        f16x8 vw;
#pragma unroll
        for (int j = 0; j < 4; ++j) {
            vw[j]     = (_Float16)(W2SCALE * w0[j]);
            vw[4 + j] = (_Float16)(W2SCALE * w1v[j]);
        }
        sm_w2[e] = vw;
    }
    {
        const float b1v = b1o[tid];
        sm_b1[tid] = b1v;
        red[tid]   = W2o[tid] * b1v;          // c0 partial
        red4[tid]  = vpart;                   // v partial
    }

    // hoist half-0 x loads
    f16x4 xf0[8];
    {
        const int tile0 = grp * 128 + w * 8;
#pragma unroll
        for (int t = 0; t < 8; ++t) {
            const f32x4 xv = *reinterpret_cast<const f32x4*>(
                x + (size_t)((tile0 + t) * 16 + col) * I_DIM + kg * 4);
            h16x2 q0 = __builtin_amdgcn_cvt_pkrtz(xv[0], xv[1]);
            h16x2 q1 = __builtin_amdgcn_cvt_pkrtz(xv[2], xv[3]);
            i32x2 xi; xi[0] = __builtin_bit_cast(int, q0); xi[1] = __builtin_bit_cast(int, q1);
            xf0[t] = __builtin_bit_cast(f16x4, xi);
        }
    }
    __syncthreads();

    // wave 0: reduce v and c0
    if (tid < 64) {
        f32x4 s = red4[tid];
#pragma unroll
        for (int k = 1; k < 8; ++k) s += red4[tid + 64 * k];
#pragma unroll
        for (int m = 1; m <= 8; m <<= 1) {
#pragma unroll
            for (int c = 0; c < 4; ++c) s[c] += __shfl_xor(s[c], m, 64);
        }
        if ((tid & 15) == 0) {
            const int kgw = tid >> 4;
#pragma unroll
            for (int j = 0; j < 4; ++j) v_sm[kgw * 4 + j] = 0.6f * s[j];
        }
        float cs = 0.f;
#pragma unroll
        for (int k = 0; k < 8; ++k) cs += red[tid + 64 * k];
#pragma unroll
        for (int m = 1; m <= 32; m <<= 1) cs += __shfl_xor(cs, m, 64);
        if (tid == 0) c_sm = 0.6f * cs + b2[o];
    }
    __syncthreads();

    // ---- phase B ----
    for (int half = 0; half < 2; ++half) {
        const int tile0 = grp * 128 + half * 64 + w * 8;

        f16x4 xf[8];
        if (half == 0) {
#pragma unroll
            for (int t = 0; t < 8; ++t) xf[t] = xf0[t];
        } else {
#pragma unroll
            for (int t = 0; t < 8; ++t) {
                const f32x4 xv = *reinterpret_cast<const f32x4*>(
                    x + (size_t)((tile0 + t) * 16 + col) * I_DIM + kg * 4);
                h16x2 q0 = __builtin_amdgcn_cvt_pkrtz(xv[0], xv[1]);
                h16x2 q1 = __builtin_amdgcn_cvt_pkrtz(xv[2], xv[3]);
                i32x2 xi; xi[0] = __builtin_bit_cast(int, q0); xi[1] = __builtin_bit_cast(int, q1);
                xf[t] = __builtin_bit_cast(f16x4, xi);
            }
        }

        f16x4 vlf;
#pragma unroll
        for (int j = 0; j < 4; ++j) vlf[j] = (_Float16)v_sm[kg * 4 + j];
        const float c0 = c_sm;
        const f32x4 linC = {c0, c0, c0, c0};

        // linear init ONCE (outside rep loop)
        f32x4 acc[8];
#pragma unroll
        for (int t = 0; t < 8; ++t)
            acc[t] = __builtin_amdgcn_mfma_f32_16x16x16f16(xf[t], vlf, linC, 0, 0, 0);

#pragma unroll 1
        for (int rep = 0; rep < LOOP_REPS; ++rep) {
            // opaque-touch xf: prevents CSE/hoist of stage-1 MFMAs across reps
#pragma unroll
            for (int t = 0; t < 8; ++t) {
                i32x2 xb = __builtin_bit_cast(i32x2, xf[t]);
                int lo = xb[0], hi = xb[1];
                asm volatile("" : "+v"(lo), "+v"(hi));
                xb[0] = lo; xb[1] = hi;
                xf[t] = __builtin_bit_cast(f16x4, xb);
            }
#pragma unroll 2
            for (int p = 0; p < 16; ++p) {
                const f16x8 a1pair = sm_a1[p * 64 + lane];
                const f16x4 A1a = __builtin_shufflevector(a1pair, a1pair, 0, 1, 2, 3);
                const f16x4 A1b = __builtin_shufflevector(a1pair, a1pair, 4, 5, 6, 7);
                const f16x8 W2f = sm_w2[p * 64 + lane];
                const f32x4 bC0 = *reinterpret_cast<const f32x4*>(&sm_b1[p * 32 + kg * 4]);
                const f32x4 bC1 = *reinterpret_cast<const f32x4*>(&sm_b1[p * 32 + 16 + kg * 4]);
#pragma unroll
                for (int t = 0; t < 8; ++t) {
                    f32x4 d0 = __builtin_amdgcn_mfma_f32_16x16x16f16(A1a, xf[t], bC0, 0, 0, 0);
                    f32x4 d1 = __builtin_amdgcn_mfma_f32_16x16x16f16(A1b, xf[t], bC1, 0, 0, 0);
                    h16x2 p0 = __builtin_amdgcn_cvt_pkrtz(fabsf(d0[0]), fabsf(d0[1]));
                    h16x2 p1 = __builtin_amdgcn_cvt_pkrtz(fabsf(d0[2]), fabsf(d0[3]));
                    h16x2 p2 = __builtin_amdgcn_cvt_pkrtz(fabsf(d1[0]), fabsf(d1[1]));
                    h16x2 p3 = __builtin_amdgcn_cvt_pkrtz(fabsf(d1[2]), fabsf(d1[3]));
                    i32x4 ai;
                    ai[0] = __builtin_bit_cast(int, p0); ai[1] = __builtin_bit_cast(int, p1);
                    ai[2] = __builtin_bit_cast(int, p2); ai[3] = __builtin_bit_cast(int, p3);
                    f16x8 A2 = __builtin_bit_cast(f16x8, ai);
                    acc[t] = __builtin_amdgcn_mfma_f32_16x16x32_f16(A2, W2f, acc[t], 0, 0, 0);
                }
            }
        }

        if (col < 4) {
#pragma unroll
            for (int t = 0; t < 8; ++t) {
                float v = (col == 0) ? acc[t][0] : (col == 1) ? acc[t][1]
                        : (col == 2) ? acc[t][2] : acc[t][3];
                out[(size_t)((tile0 + t) * 16 + kg * 4 + col) * O_DIM + o] = v;
            }
        }
    }
}

extern "C" void kernel_launch(void* const* d_in, const int* in_sizes, int n_in,
                              void* d_out, int out_size, void* d_ws, size_t ws_size,
                              hipStream_t stream) {
    const float* x  = (const float*)d_in[0];
    const float* W1 = (const float*)d_in[1];
    const float* b1 = (const float*)d_in[2];
    const float* W2 = (const float*)d_in[3];
    const float* b2 = (const float*)d_in[4];
    float* out = (float*)d_out;

    mlp_fused<<<256, 512, 0, stream>>>(x, W1, b1, W2, b2, out);
}

// Round 24
// 27.881 us; speedup vs baseline: 2.5005x; 2.5005x over previous
//
#include <hip/hip_runtime.h>

// out[b,o] = sum_h W2[o,h]*leaky(h) + b2[o],  h = W1[o]·x[b] + b1[o]
// leaky(t) = 0.6t + 0.4|t|
//   out[b,o] = 0.6(v[o]·x[b]) + c0[o] + sum_h (0.4 W2[o,h])|h|
// R25: R24's counters (MfmaUtil 56%, ~13cyc/MFMA measured) showed the loop is
// bound by the LEGACY 16x16x16 MFMA shape. This round:
//  - stage1 = mfma_f32_32x32x16_f16 (full-rate m119 shape, ~8cyc, 4x the
//    work of one 16x16x16): d[r] = h[p*32 + R(r,hi)] for b=lane&31,
//    R(r,hi)=(r&3)+8(r>>2)+4hi (validated end-to-end by R14's passing run);
//    b1 rides the f32-C operand (bC[r]=b1[p*32+R(r,hi)], LDS-permuted).
//  - stage2 = 16 f32 FMAs on d with FREE |.| modifier, w2 LDS-permuted to
//    the same D-layout. ZERO cvt_pkrtz in the loop (f16 repack deleted).
//  - linear part: per-lane half-dot in nlv init; the shfl_xor(32) merging
//    the two hi-halves of h also merges the two lin halves.
// Spill discipline (R14-R19 taxonomy): weights LDS-resident, unroll-1 p-loop
// (runtime LDS idx legal), static reg indexing only; peak live ~114 < 128.

#define H_DIM 512

typedef _Float16 f16x8  __attribute__((ext_vector_type(8)));
typedef __fp16   h16x2  __attribute__((ext_vector_type(2)));   // cvt_pkrtz native
typedef float    f32x4  __attribute__((ext_vector_type(4)));
typedef float    f32x16 __attribute__((ext_vector_type(16)));
typedef int      i32x4  __attribute__((ext_vector_type(4)));

// 256 blocks x 512 thr (8 waves), 1 block/CU. o = blk&15, grp = blk>>4 (16).
// Block: 2048 batch rows; wave: 256 rows = 2 halves x 4 tile-pairs of 32.
__global__ __launch_bounds__(512, 2) void mlp_fused(
    const float* __restrict__ x, const float* __restrict__ W1,
    const float* __restrict__ b1, const float* __restrict__ W2,
    const float* __restrict__ b2, float* __restrict__ out) {
    __shared__ f16x8 sm_a1[1024];     // [p][lane] W1 frags (32x32x16 A) 16 KiB
    __shared__ float sm_b1p[512];     // [p][hi][r] b1 in D-layout        2 KiB
    __shared__ float sm_w2p[512];     // [p][hi][r] 0.4*W2 in D-layout    2 KiB
    __shared__ float redv[512];       //  2 KiB
    __shared__ float redc[512];       //  2 KiB
    __shared__ float v_sm[16];
    __shared__ float c_sm;

    const int tid = threadIdx.x;
    const int o   = blockIdx.x & 15;
    const int grp = blockIdx.x >> 4;
    const float* W1o = W1 + (size_t)o * H_DIM * 16;
    const float* W2o = W2 + (size_t)o * H_DIM;
    const float* b1o = b1 + (size_t)o * H_DIM;

    const int lane = tid & 63, w = tid >> 6;
    const int c = lane & 31, hi = lane >> 5;

    // ---- phase A ----
    // A-frags: lane l: row h_loc=l&31, k=(l>>5)*8+j -> W1[p*32+(l&31)][(l>>5)*8+j]
#pragma unroll
    for (int i = 0; i < 2; ++i) {
        const int e = tid + 512 * i;          // 0..1023 = [p][lane]
        const int l = e & 63, p = e >> 6;
        const float* src = W1o + (size_t)(p * 32 + (l & 31)) * 16 + (l >> 5) * 8;
        const f32x4 a0 = *reinterpret_cast<const f32x4*>(src);
        const f32x4 a1v = *reinterpret_cast<const f32x4*>(src + 4);
        h16x2 q0 = __builtin_amdgcn_cvt_pkrtz(a0[0], a0[1]);
        h16x2 q1 = __builtin_amdgcn_cvt_pkrtz(a0[2], a0[3]);
        h16x2 q2 = __builtin_amdgcn_cvt_pkrtz(a1v[0], a1v[1]);
        h16x2 q3 = __builtin_amdgcn_cvt_pkrtz(a1v[2], a1v[3]);
        i32x4 vi;
        vi[0] = __builtin_bit_cast(int, q0); vi[1] = __builtin_bit_cast(int, q1);
        vi[2] = __builtin_bit_cast(int, q2); vi[3] = __builtin_bit_cast(int, q3);
        sm_a1[e] = __builtin_bit_cast(f16x8, vi);
    }
    // b1/w2 permuted to the 32x32 D-layout: entry (p*2+hh)*16+r, h=p*32+R(r,hh)
    {
        const int p = tid >> 5, hh = (tid >> 4) & 1, r = tid & 15;
        const int h = p * 32 + (r & 3) + 8 * (r >> 2) + 4 * hh;
        sm_b1p[tid] = b1o[h];
        sm_w2p[tid] = 0.4f * W2o[h];
    }
    // v partials (R20-style) + c0 partials
    {
        const int i = tid & 15, hc = tid >> 4;     // 32 chunks x 16 h
        float a = 0.f;
#pragma unroll
        for (int hh = 0; hh < 16; ++hh) {
            const int h = hc * 16 + hh;
            a = fmaf(W2o[h], W1o[(size_t)h * 16 + i], a);
        }
        redv[tid] = a;
        redc[tid] = W2o[tid] * b1o[tid];
    }
    __syncthreads();
    if (tid < 16) {
        float s = 0.f;
#pragma unroll
        for (int k = 0; k < 32; ++k) s += redv[tid + 16 * k];
        v_sm[tid] = 0.6f * s;
    }
    if (tid < 64) {
        float cs = 0.f;
#pragma unroll
        for (int k = 0; k < 8; ++k) cs += redc[tid + 64 * k];
#pragma unroll
        for (int m = 1; m <= 32; m <<= 1) cs += __shfl_xor(cs, m, 64);
        if (tid == 0) c_sm = 0.6f * cs + b2[o];
    }
    __syncthreads();

    // ---- phase B ----
    const float c0 = c_sm;
    const f32x4 vh0 = *reinterpret_cast<const f32x4*>(&v_sm[hi * 8]);
    const f32x4 vh1 = *reinterpret_cast<const f32x4*>(&v_sm[hi * 8 + 4]);

    for (int half = 0; half < 2; ++half) {
        const int rbase = grp * 2048 + half * 1024 + w * 128 + c;

        // x load: row b = rbase+tp*32, this lane's 8 cols [hi*8, hi*8+8)
        f16x8 xf[4];
        f32x4 nlv[4];
#pragma unroll
        for (int tp = 0; tp < 4; ++tp) {
            const float* xp = x + (size_t)(rbase + tp * 32) * 16 + hi * 8;
            const f32x4 x0 = *reinterpret_cast<const f32x4*>(xp);
            const f32x4 x1 = *reinterpret_cast<const f32x4*>(xp + 4);
            nlv[tp] = x0 * vh0 + x1 * vh1;       // exact-f32 lin half (this hi)
            h16x2 q0 = __builtin_amdgcn_cvt_pkrtz(x0[0], x0[1]);
            h16x2 q1 = __builtin_amdgcn_cvt_pkrtz(x0[2], x0[3]);
            h16x2 q2 = __builtin_amdgcn_cvt_pkrtz(x1[0], x1[1]);
            h16x2 q3 = __builtin_amdgcn_cvt_pkrtz(x1[2], x1[3]);
            i32x4 xi;
            xi[0] = __builtin_bit_cast(int, q0); xi[1] = __builtin_bit_cast(int, q1);
            xi[2] = __builtin_bit_cast(int, q2); xi[3] = __builtin_bit_cast(int, q3);
            xf[tp] = __builtin_bit_cast(f16x8, xi);
        }

#pragma unroll 1
        for (int p = 0; p < 16; ++p) {
            const f16x8 A1 = sm_a1[p * 64 + lane];
            const float* bp = &sm_b1p[(p * 2 + hi) * 16];   // broadcast (hi-only)
            const float* wp = &sm_w2p[(p * 2 + hi) * 16];
            const f32x4 b0 = *reinterpret_cast<const f32x4*>(bp);
            const f32x4 b1q = *reinterpret_cast<const f32x4*>(bp + 4);
            const f32x4 b2q = *reinterpret_cast<const f32x4*>(bp + 8);
            const f32x4 b3q = *reinterpret_cast<const f32x4*>(bp + 12);
            const f32x4 w0 = *reinterpret_cast<const f32x4*>(wp);
            const f32x4 w1q = *reinterpret_cast<const f32x4*>(wp + 4);
            const f32x4 w2q = *reinterpret_cast<const f32x4*>(wp + 8);
            const f32x4 w3q = *reinterpret_cast<const f32x4*>(wp + 12);
            f32x16 bC;
#pragma unroll
            for (int e = 0; e < 4; ++e) {
                bC[e] = b0[e]; bC[4 + e] = b1q[e]; bC[8 + e] = b2q[e]; bC[12 + e] = b3q[e];
            }
#pragma unroll
            for (int tp = 0; tp < 4; ++tp) {
                // stage1: d[r] = h[p*32 + R(r,hi)] (bias inside via C) for b=c
                const f32x16 d = __builtin_amdgcn_mfma_f32_32x32x16_f16(A1, xf[tp], bC, 0, 0, 0);
                // stage2: 16 FMAs, |d| is a free VOP3 source modifier
#pragma unroll
                for (int e = 0; e < 4; ++e) {
                    nlv[tp][e] = fmaf(w0[e],  fabsf(d[e]),      nlv[tp][e]);
                    nlv[tp][e] = fmaf(w1q[e], fabsf(d[4 + e]),  nlv[tp][e]);
                    nlv[tp][e] = fmaf(w2q[e], fabsf(d[8 + e]),  nlv[tp][e]);
                    nlv[tp][e] = fmaf(w3q[e], fabsf(d[12 + e]), nlv[tp][e]);
                }
            }
        }

        // epilogue: lane and lane^32 hold complementary h-halves AND lin-halves
#pragma unroll
        for (int tp = 0; tp < 4; ++tp) {
            float s = nlv[tp][0] + nlv[tp][1] + nlv[tp][2] + nlv[tp][3];
            s += __shfl_xor(s, 32, 64);
            if (hi == 0)
                out[(size_t)(rbase + tp * 32) * 16 + o] = s + c0;
        }
    }
}

extern "C" void kernel_launch(void* const* d_in, const int* in_sizes, int n_in,
                              void* d_out, int out_size, void* d_ws, size_t ws_size,
                              hipStream_t stream) {
    const float* x  = (const float*)d_in[0];
    const float* W1 = (const float*)d_in[1];
    const float* b1 = (const float*)d_in[2];
    const float* W2 = (const float*)d_in[3];
    const float* b2 = (const float*)d_in[4];
    float* out = (float*)d_out;

    mlp_fused<<<256, 512, 0, stream>>>(x, W1, b1, W2, b2, out);
}